// Round 9
// baseline (457.738 us; speedup 1.0000x reference)
//
#include <hip/hip_runtime.h>
#include <hip/hip_bf16.h>
#include <stdint.h>

// ---------------- problem constants (from setup_inputs) ----------------
constexpr int Mrows = 8192;   // B*S
constexpr int Hdim  = 2048;   // K of main GEMM
constexpr int Sdim  = 4096;
constexpr int HnD   = 4096;   // Hn*D
constexpr int Hn    = 32;
constexpr int Dd    = 128;
constexpr int Lc    = 16384;
constexpr int NFULL = 4352;   // staged B' rows: 4096 q + 128 k + 32 w + pad

typedef unsigned short u16;
typedef __attribute__((ext_vector_type(8))) short    bf16x8;
typedef __attribute__((ext_vector_type(4))) float    f32x4;
typedef __attribute__((ext_vector_type(8))) unsigned short u16x8;

__device__ __forceinline__ u16 f2bf(float f) {
    union { float f; unsigned int i; } v; v.f = f;
    unsigned int x = v.i;
    return (u16)((x + 0x7fffu + ((x >> 16) & 1u)) >> 16);   // RNE
}
__device__ __forceinline__ void gload_lds16(const void* g, void* l) {
    __builtin_amdgcn_global_load_lds(
        (const __attribute__((address_space(1))) void*)g,
        (__attribute__((address_space(3))) void*)l, 16, 0, 0);
}

// ---------------- 1) fused prep: stats | prep_wt | transpose_h | bg_dot | copy
// LDS tile stride 66 (was 72): 72-elem stride put the 16-row column reads in
// 8 banks (8-way conflict); 33-word stride spreads to ~2-way (free).
__global__ __launch_bounds__(256) void fused_prep(
    const float* __restrict__ x, u16* __restrict__ xb, float* __restrict__ rms,
    float* __restrict__ mu, float* __restrict__ rstd,
    const float* __restrict__ wqb, const float* __restrict__ qn, const float* __restrict__ qns,
    const float* __restrict__ wk,  const float* __restrict__ g,  const float* __restrict__ wproj,
    u16* __restrict__ wt,
    const float* __restrict__ hq, const float* __restrict__ hk,
    u16* __restrict__ hqt, u16* __restrict__ hkt,
    const float* __restrict__ b,
    float* __restrict__ bdot, float* __restrict__ gdot,
    const float* __restrict__ kc, const float* __restrict__ kcs,
    float* __restrict__ dk, float* __restrict__ dks)
{
    __shared__ u16 utile[64 * 66];
    __shared__ float sred[8];
    int bid = blockIdx.x, t = threadIdx.x;

    if (bid < 8192) {
        // ---- per-row stats + fp32->bf16 copy of x ----
        int r = bid;
        const float4* xr = (const float4*)(x + (size_t)r * Hdim);
        float4 a4 = xr[2 * t], b4 = xr[2 * t + 1];
        float v[8] = {a4.x, a4.y, a4.z, a4.w, b4.x, b4.y, b4.z, b4.w};
        float s = 0.f, ss = 0.f;
        __align__(16) u16 o[8];
        #pragma unroll
        for (int i = 0; i < 8; i++) { s += v[i]; ss += v[i] * v[i]; o[i] = f2bf(v[i]); }
        ((u16x8*)(xb + (size_t)r * Hdim))[t] = *(const u16x8*)o;
        for (int oo = 32; oo > 0; oo >>= 1) { s += __shfl_down(s, oo); ss += __shfl_down(ss, oo); }
        if ((t & 63) == 0) { sred[t >> 6] = s; sred[4 + (t >> 6)] = ss; }
        __syncthreads();
        if (t == 0) {
            float S1 = sred[0] + sred[1] + sred[2] + sred[3];
            float S2 = sred[4] + sred[5] + sred[6] + sred[7];
            float mean = S1 / Hdim, msq = S2 / Hdim;
            rms[r]  = rsqrtf(msq + 1e-6f);
            mu[r]   = mean;
            rstd[r] = rsqrtf(msq - mean * mean + 1e-6f);
        }
    } else if (bid < 10368) {
        // ---- build B'^T = [c1*wqb | g*wk | wproj | 0]^T ----
        int b2 = bid - 8192;
        int k0 = (b2 & 31) * 64, n0 = (b2 >> 5) * 64;
        int lk = t >> 2, lc0 = (t & 3) * 16;
        int k = k0 + lk;
        float c1k = qn[k] * qns[k];
        float gk  = g[k];
        #pragma unroll
        for (int i = 0; i < 16; i++) {
            int n = n0 + lc0 + i;
            float val;
            if (n < 4096)      val = wqb[(size_t)k * HnD + n] * c1k;
            else if (n < 4224) val = wk[k * Dd + (n - 4096)] * gk;
            else if (n < 4256) val = wproj[k * Hn + (n - 4224)];
            else               val = 0.f;
            utile[lk * 66 + lc0 + i] = f2bf(val);
        }
        __syncthreads();
        int ln = t >> 2, lk0 = (t & 3) * 16;
        __align__(16) u16 o[16];
        #pragma unroll
        for (int i = 0; i < 16; i++) o[i] = utile[(lk0 + i) * 66 + ln];
        u16* dst = wt + (size_t)(n0 + ln) * Hdim + k0 + lk0;
        *(u16x8*)dst = *(const u16x8*)o;
        *(u16x8*)(dst + 8) = *((const u16x8*)o + 1);
    } else if (bid < 10376) {
        // ---- hadamard transpose to bf16: 64x64 tiles ----
        int q = bid - 10368;
        int matq = q >> 2, tr = (q >> 1) & 1, tc = q & 1;
        const float* src = matq ? hk : hq;
        u16* dst = matq ? hkt : hqt;
        int r = t >> 2, c0 = (t & 3) * 16;
        #pragma unroll
        for (int i = 0; i < 4; i++) {
            float4 vv = *(const float4*)(src + (size_t)(tr * 64 + r) * Dd + tc * 64 + c0 + 4 * i);
            utile[r * 66 + c0 + 4 * i]     = f2bf(vv.x);
            utile[r * 66 + c0 + 4 * i + 1] = f2bf(vv.y);
            utile[r * 66 + c0 + 4 * i + 2] = f2bf(vv.z);
            utile[r * 66 + c0 + 4 * i + 3] = f2bf(vv.w);
        }
        __syncthreads();
        int n = t >> 2, k0 = (t & 3) * 16;
        __align__(16) u16 o[16];
        #pragma unroll
        for (int i = 0; i < 16; i++) o[i] = utile[(k0 + i) * 66 + n];
        u16* dp = dst + (size_t)(tc * 64 + n) * Dd + tr * 64 + k0;
        *(u16x8*)dp = *(const u16x8*)o;
        *(u16x8*)(dp + 8) = *((const u16x8*)o + 1);
    } else if (bid < 10504) {
        // ---- bdot/gdot ----
        int n = bid - 10376;
        float sb = 0.f, sg = 0.f;
        for (int k = t; k < Hdim; k += 256) {
            float w = wk[k * Dd + n];
            sb += b[k] * w;
            sg += g[k] * w;
        }
        for (int o = 32; o > 0; o >>= 1) { sb += __shfl_down(sb, o); sg += __shfl_down(sg, o); }
        if ((t & 63) == 0) { sred[t >> 6] = sb; sred[4 + (t >> 6)] = sg; }
        __syncthreads();
        if (t == 0) {
            bdot[n] = sred[0] + sred[1] + sred[2] + sred[3];
            gdot[n] = sred[4] + sred[5] + sred[6] + sred[7];
        }
    } else {
        // ---- copy cache defaults into outputs ----
        int gg = (bid - 10504) * 256 + t;
        ((float4*)dk)[2 * gg]     = ((const float4*)kc)[2 * gg];
        ((float4*)dk)[2 * gg + 1] = ((const float4*)kc)[2 * gg + 1];
        if (gg < Lc / 8) {
            ((float4*)dks)[2 * gg]     = ((const float4*)kcs)[2 * gg];
            ((float4*)dks)[2 * gg + 1] = ((const float4*)kcs)[2 * gg + 1];
        }
    }
}

// ---------------- 2) main fused q-GEMM: R6 8-phase schedule, relaxed lgkm ---
// BM=BN=256, BK=64, 512 thr = 8 waves (4M x 2N: wave = 64 rows x one 128-col
// head -> in-register RoPE partner nt^4). LDS 128 KiB dbuf; per tile 4 stage
// units {A-K0, A-K1, B-K0, B-K1} of 256 rows x 32 K (2 loads/thread each).
// 8 phases per 2 K-tiles: {ds_read frags || 1 stage unit -> 16 MFMA (setprio)
// -> barrier}; NO forced lgkmcnt(0) (R7/k_branch evidence: compiler's
// fine-grained lgkmcnt(N) lets the first MFMA start when its own operands
// land; forcing 0 serializes). Each phase ends with a ZERO-COST compiler
// memory fence (asm ""::memory) before the raw s_barrier — raw s_barrier has
// no fence semantics, LDS ops could otherwise cross it (the old asm waitcnts
// provided this accidentally). Counted vmcnt(6) only at phases 4 & 8.
// Region re-stage only in the phase after its last read (barrier-separated).
// Race-safety of relaxed lgkm: every ds_read is consumed by an MFMA before
// the phase barrier, so compiler waits drain all reads pre-barrier.
#define RA(bufo, ks, mt) (*(const bf16x8*)(lds + (bufo) * 65536 + (ks) * 16384 + \
    (wr * 64 + (mt) * 16 + l15) * 64 + rsw))
#define RB(bufo, ks, nh, j) (*(const bf16x8*)(lds + (bufo) * 65536 + 32768 + (ks) * 16384 + \
    (wc * 128 + (nh) * 64 + (j) * 16 + l15) * 64 + rsw))
#define SA(tt, ks) do { \
    const u16* gp_ = Ab + (size_t)srow * Hdim + (tt) * 64 + (ks) * 32 + scol; \
    char* dp_ = lds + (((tt) & 1) * 65536) + (ks) * 16384 + wq; \
    gload_lds16(gp_, dp_); \
    gload_lds16(gp_ + (size_t)128 * Hdim, dp_ + 8192); \
} while (0)
#define SB(tt, ks) do { \
    const u16* gp_ = Bb + (size_t)srow * Hdim + (tt) * 64 + (ks) * 32 + scol; \
    char* dp_ = lds + (((tt) & 1) * 65536) + 32768 + (ks) * 16384 + wq; \
    gload_lds16(gp_, dp_); \
    gload_lds16(gp_ + (size_t)128 * Hdim, dp_ + 8192); \
} while (0)
#define VM6 asm volatile("s_waitcnt vmcnt(6)" ::: "memory")
#define VM0 asm volatile("s_waitcnt vmcnt(0)" ::: "memory")
#define NOPS ((void)0)
#define PH(bufo, ks, nh, STG, WT) do { \
    if ((nh) == 0) { \
        _Pragma("unroll") for (int mt = 0; mt < 4; mt++) af[mt] = RA(bufo, ks, mt); \
    } \
    _Pragma("unroll") for (int j = 0; j < 4; j++) bfr[j] = RB(bufo, ks, nh, j); \
    STG; \
    __builtin_amdgcn_s_setprio(1); \
    _Pragma("unroll") for (int mt = 0; mt < 4; mt++) \
        _Pragma("unroll") for (int j = 0; j < 4; j++) \
            acc[mt][(nh) * 4 + j] = __builtin_amdgcn_mfma_f32_16x16x32_bf16( \
                af[mt], bfr[j], acc[mt][(nh) * 4 + j], 0, 0, 0); \
    __builtin_amdgcn_s_setprio(0); \
    WT; \
    asm volatile("" ::: "memory"); \
    __builtin_amdgcn_s_barrier(); \
} while (0)

__global__ __launch_bounds__(512, 1) void main_gemm(
    const u16* __restrict__ A, const u16* __restrict__ Bt,
    const float* __restrict__ rms, const float* __restrict__ qbs,
    const u16* __restrict__ hqt,
    const float* __restrict__ cosr, const float* __restrict__ sinr,
    float* __restrict__ oq, float* __restrict__ oqs)
{
    __shared__ __align__(16) char lds[131072];

    int tid = threadIdx.x;
    int w = tid >> 6, lane = tid & 63, quad = lane >> 4, l15 = lane & 15;
    int wr = w & 3, wc = w >> 2;                 // 4 M-waves x 2 N-waves
    int bm = blockIdx.x, bn = blockIdx.y;
    int brow = bm * 256;
    int rsw = (quad ^ ((l15 >> 1) & 3)) * 16;    // read-side 16B-slot swizzle

    const u16* Ab = A  + (size_t)brow * Hdim;
    const u16* Bb = Bt + (size_t)(bn * 256) * Hdim;

    // staging: unit = 256 rows x 32 K; thread loads rows srow, srow+128
    int srow = tid >> 2;                         // 0..127
    int scol = (((tid & 3) ^ ((srow >> 1) & 3)) * 8);   // pre-swizzled chunk
    int wq = w * 1024;                           // wave-uniform dest part

    bf16x8 af[4], bfr[4];
    f32x4 acc[4][8] = {};

    // prologue: units AK0(0),BK0(0),AK1(0),BK1(0),AK0(1),BK0(1),AK1(1)
    SA(0, 0); SB(0, 0); SA(0, 1); SB(0, 1); SA(1, 0); SB(1, 0); SA(1, 1);
    VM6;                                         // tile 0 fully landed
    __builtin_amdgcn_s_barrier();

    for (int I = 0; I < 15; I++) {
        int t1 = 2 * I + 1, t2 = 2 * I + 2, t3 = 2 * I + 3;
        PH(0, 0, 0, SB(t1, 1), NOPS);            // stage BK1(t+1)
        PH(0, 0, 1, SA(t2, 0), NOPS);            // AK0(t+2)
        PH(0, 1, 0, SB(t2, 0), NOPS);            // BK0(t+2)
        PH(0, 1, 1, SA(t2, 1), VM6);             // AK1(t+2); t+1 complete
        PH(1, 0, 0, SB(t2, 1), NOPS);            // BK1(t+2)
        PH(1, 0, 1, SA(t3, 0), NOPS);            // AK0(t+3)
        PH(1, 1, 0, SB(t3, 0), NOPS);            // BK0(t+3)
        PH(1, 1, 1, SA(t3, 1), VM6);             // AK1(t+3); t+2 K0 complete
    }
    // peeled last iter: t = 30, 31
    PH(0, 0, 0, SB(31, 1), NOPS);                // stage BK1(31) (last unit)
    PH(0, 0, 1, NOPS, NOPS);
    PH(0, 1, 0, NOPS, NOPS);
    PH(0, 1, 1, NOPS, VM0);                      // drain: tile 31 all landed
    PH(1, 0, 0, NOPS, NOPS);
    PH(1, 0, 1, NOPS, NOPS);
    PH(1, 1, 0, NOPS, NOPS);
    PH(1, 1, 1, NOPS, NOPS);

    // -------- fused q epilogue: scale -> RoPE -> P (per-wave LDS, swizzled)
    //          -> hadamard MFMA -> absmax -> quant -> store
    __syncthreads();
    int head = bn * 2 + wc;                      // 0..31
    char* Pw = lds + w * 16384;                  // per-wave [64][256B] region
    float qb[8];
    #pragma unroll
    for (int nt = 0; nt < 8; nt++) qb[nt] = qbs[head * 128 + nt * 16 + l15];
    #pragma unroll
    for (int mt = 0; mt < 4; mt++) {
        float y[8][4];
        #pragma unroll
        for (int reg = 0; reg < 4; reg++) {
            float rv = rms[brow + wr * 64 + mt * 16 + quad * 4 + reg];
            #pragma unroll
            for (int nt = 0; nt < 8; nt++) y[nt][reg] = acc[mt][nt][reg] * rv * qb[nt];
        }
        #pragma unroll
        for (int reg = 0; reg < 4; reg++) {
            int rp = mt * 16 + quad * 4 + reg;          // 0..63 local row
            int s_ = (brow + wr * 64 + rp) & (Sdim - 1);
            const float* cr = cosr + (size_t)s_ * Dd + l15;
            const float* sr = sinr + (size_t)s_ * Dd + l15;
            int sw = (rp & 7) << 4;
            #pragma unroll
            for (int nt = 0; nt < 8; nt++) {
                float c  = cr[nt * 16];
                float sv = sr[nt * 16];
                float sign = (nt < 4) ? -1.f : 1.f;
                float o = y[nt][reg] * c + sign * y[nt ^ 4][reg] * sv;   // fp32 RoPE
                int colb = (nt * 16 + l15) * 2;
                *(u16*)(Pw + rp * 256 + (colb ^ sw)) = f2bf(o);
            }
        }
    }
    __syncthreads();
    #pragma unroll
    for (int mt = 0; mt < 4; mt++) {
        bf16x8 pa[4];
        #pragma unroll
        for (int kb = 0; kb < 4; kb++) {
            int row = mt * 16 + l15;
            pa[kb] = *(const bf16x8*)(Pw + row * 256 + ((kb * 64 + quad * 16) ^ ((row & 7) << 4)));
        }
        f32x4 a2[8] = {};
        #pragma unroll
        for (int nt = 0; nt < 8; nt++) {
            #pragma unroll
            for (int kb = 0; kb < 4; kb++) {
                bf16x8 hb = *(const bf16x8*)(hqt + (size_t)(nt * 16 + l15) * Dd + kb * 32 + quad * 8);
                a2[nt] = __builtin_amdgcn_mfma_f32_16x16x32_bf16(pa[kb], hb, a2[nt], 0, 0, 0);
            }
        }
        #pragma unroll
        for (int reg = 0; reg < 4; reg++) {
            float m = 0.f;
            #pragma unroll
            for (int nt = 0; nt < 8; nt++) m = fmaxf(m, fabsf(a2[nt][reg]));
            m = fmaxf(m, __shfl_xor(m, 8));
            m = fmaxf(m, __shfl_xor(m, 4));
            m = fmaxf(m, __shfl_xor(m, 2));
            m = fmaxf(m, __shfl_xor(m, 1));
            float scale = fmaxf(m * (1.f / 127.f), 1e-8f);
            float inv = 1.f / scale;
            int r = brow + wr * 64 + mt * 16 + quad * 4 + reg;
            float* orow = oq + (size_t)r * HnD + head * 128;
            #pragma unroll
            for (int nt = 0; nt < 8; nt++)
                orow[nt * 16 + l15] = rintf(a2[nt][reg] * inv);
            if (l15 == 0) oqs[(size_t)r * Hn + head] = scale;
        }
    }
}

// ---------------- 3) k_branch: kw-GEMM + LN-affine + RoPE + hadamard + quant
__global__ __launch_bounds__(256) void k_branch(
    const u16* __restrict__ A, const u16* __restrict__ Bt,
    const float* __restrict__ rstd, const float* __restrict__ mu,
    const float* __restrict__ bdot, const float* __restrict__ gdot,
    const u16* __restrict__ hkt,
    const float* __restrict__ cosr, const float* __restrict__ sinr,
    const int* __restrict__ idx,
    float* __restrict__ ok, float* __restrict__ oks, float* __restrict__ wout)
{
    __shared__ __align__(16) char klds[73728];   // 3 slots x (A 4KB + B 20KB)
    __shared__ float pamax[32][2];
    __shared__ int sidx[32];
    int tid = threadIdx.x, w = tid >> 6, lane = tid & 63, quad = lane >> 4, l15 = lane & 15;
    int blk = blockIdx.x;
    int mh = w & 1, ngrp = w >> 1;
    const u16* Ab = A + (size_t)(blk * 32) * Hdim;
    const u16* Bb = Bt + (size_t)4096 * Hdim;
    int F[5];
    F[0] = ngrp * 2; F[1] = ngrp * 2 + 1; F[2] = 4 + ngrp * 2; F[3] = 5 + ngrp * 2; F[4] = 8 + ngrp;
    int ar = tid >> 3, ach = ((tid & 7) ^ (ar & 7)) * 8;   // pre-swizzled A chunk
    int wq1 = w * 1024;

#define KSTG(slotn, st) do { \
    gload_lds16(Ab + (size_t)ar * Hdim + (st) * 64 + ach, klds + (slotn) * 24576 + wq1); \
    _Pragma("unroll") for (int u = 0; u < 5; u++) { \
        int ix = u * 256 + tid; int br = ix >> 3; int bch = ((ix & 7) ^ (br & 7)) * 8; \
        gload_lds16(Bb + (size_t)br * Hdim + (st) * 64 + bch, \
                    klds + (slotn) * 24576 + 4096 + u * 4096 + wq1); \
    } \
} while (0)
#define KRA(slotn, ks) (*(const bf16x8*)(klds + (slotn) * 24576 + \
    (mh * 16 + l15) * 128 + ((((ks) * 4 + quad) ^ (l15 & 7)) * 16)))
#define KRB(slotn, ks, f) (*(const bf16x8*)(klds + (slotn) * 24576 + 4096 + \
    ((f) * 16 + l15) * 128 + ((((ks) * 4 + quad) ^ (l15 & 7)) * 16)))

    f32x4 acc[5] = {};
    KSTG(0, 0); KSTG(1, 1);
    asm volatile("s_waitcnt vmcnt(6)" ::: "memory");
    __builtin_amdgcn_s_barrier();
    int sl = 0;
    for (int s = 0; s < 32; s++) {
        bf16x8 ka[2], kbf[2][5];
        ka[0] = KRA(sl, 0); ka[1] = KRA(sl, 1);
        #pragma unroll
        for (int j = 0; j < 5; j++) { kbf[0][j] = KRB(sl, 0, F[j]); kbf[1][j] = KRB(sl, 1, F[j]); }
        if (s + 2 < 32) { int ns = sl + 2; if (ns >= 3) ns -= 3; KSTG(ns, s + 2); }
        __builtin_amdgcn_s_setprio(1);
        #pragma unroll
        for (int ks = 0; ks < 2; ks++)
            #pragma unroll
            for (int j = 0; j < 5; j++)
                acc[j] = __builtin_amdgcn_mfma_f32_16x16x32_bf16(ka[ks], kbf[ks][j], acc[j], 0, 0, 0);
        __builtin_amdgcn_s_setprio(0);
        if (s < 30) { asm volatile("s_waitcnt vmcnt(6)" ::: "memory"); }
        else        { asm volatile("s_waitcnt vmcnt(0)" ::: "memory"); }
        __builtin_amdgcn_s_barrier();
        sl++; if (sl == 3) sl = 0;
    }

    if (tid < 32) sidx[tid] = idx[blk * 32 + tid];
    __syncthreads();                    // GEMM LDS reads done; overlay P
    u16* sP = (u16*)klds;               // [32][136]
    #pragma unroll
    for (int reg = 0; reg < 4; reg++) {
        int rl = mh * 16 + quad * 4 + reg;
        int r = blk * 32 + rl;
        float sd = rstd[r], m_ = mu[r];
        int s_ = r & (Sdim - 1);
        float v[4];
        #pragma unroll
        for (int j = 0; j < 4; j++) {
            int col = F[j] * 16 + l15;
            v[j] = acc[j][reg] * sd + bdot[col] - sd * m_ * gdot[col];
        }
        #pragma unroll
        for (int j = 0; j < 4; j++) {
            int col = F[j] * 16 + l15;
            float c = cosr[(size_t)s_ * Dd + col], sv = sinr[(size_t)s_ * Dd + col];
            float sign = (j < 2) ? -1.f : 1.f;
            sP[rl * 136 + col] = f2bf(v[j] * c + sign * v[j ^ 2] * sv);   // fp32 RoPE
        }
        wout[(size_t)r * Hn + (F[4] - 8) * 16 + l15] = acc[4][reg];
    }
    __syncthreads();
    f32x4 a2[4] = {};
    #pragma unroll
    for (int kb4 = 0; kb4 < 4; kb4++) {
        bf16x8 pa = *(const bf16x8*)(sP + (mh * 16 + l15) * 136 + kb4 * 32 + quad * 8);
        #pragma unroll
        for (int nt = 0; nt < 4; nt++) {
            bf16x8 hb = *(const bf16x8*)(hkt + (size_t)(ngrp * 64 + nt * 16 + l15) * Dd + kb4 * 32 + quad * 8);
            a2[nt] = __builtin_amdgcn_mfma_f32_16x16x32_bf16(pa, hb, a2[nt], 0, 0, 0);
        }
    }
    #pragma unroll
    for (int reg = 0; reg < 4; reg++) {
        float m = 0.f;
        #pragma unroll
        for (int nt = 0; nt < 4; nt++) m = fmaxf(m, fabsf(a2[nt][reg]));
        m = fmaxf(m, __shfl_xor(m, 8));
        m = fmaxf(m, __shfl_xor(m, 4));
        m = fmaxf(m, __shfl_xor(m, 2));
        m = fmaxf(m, __shfl_xor(m, 1));
        if (l15 == 0) pamax[mh * 16 + quad * 4 + reg][ngrp] = m;
    }
    __syncthreads();
    #pragma unroll
    for (int reg = 0; reg < 4; reg++) {
        int rl = mh * 16 + quad * 4 + reg;
        float am = fmaxf(pamax[rl][0], pamax[rl][1]);
        float scale = fmaxf(am * (1.f / 127.f), 1e-8f);
        float inv = 1.f / scale;
        size_t dro = (size_t)sidx[rl] * Dd;
        #pragma unroll
        for (int nt = 0; nt < 4; nt++)
            ok[dro + ngrp * 64 + nt * 16 + l15] = rintf(a2[nt][reg] * inv);
        if (l15 == 0 && ngrp == 0) oks[sidx[rl]] = scale;
    }
}

// ---------------- launch ------------------------------------------------
extern "C" void kernel_launch(void* const* d_in, const int* in_sizes, int n_in,
                              void* d_out, int out_size, void* d_ws, size_t ws_size,
                              hipStream_t stream) {
    (void)in_sizes; (void)n_in; (void)out_size; (void)ws_size;
    const float* x    = (const float*)d_in[0];
    const float* qn   = (const float*)d_in[1];
    const float* qns  = (const float*)d_in[2];
    const float* wqb  = (const float*)d_in[3];
    const float* wqbs = (const float*)d_in[4];
    const float* wk   = (const float*)d_in[5];
    const float* wpj  = (const float*)d_in[6];
    const float* g    = (const float*)d_in[7];
    const float* b    = (const float*)d_in[8];
    const float* cosr = (const float*)d_in[9];
    const float* sinr = (const float*)d_in[10];
    const float* hq   = (const float*)d_in[11];
    const float* hk   = (const float*)d_in[12];
    const float* kc   = (const float*)d_in[13];
    const float* kcs  = (const float*)d_in[14];
    const int*   idx  = (const int*)d_in[15];

    // ws layout
    char* ws = (char*)d_ws;
    size_t o = 0;
    u16* xb  = (u16*)(ws + o); o += (size_t)Mrows * Hdim * 2;   // 33.55 MB
    u16* wt  = (u16*)(ws + o); o += (size_t)NFULL * Hdim * 2;   // 17.83 MB
    u16* hqt = (u16*)(ws + o); o += Dd * Dd * 2;
    u16* hkt = (u16*)(ws + o); o += Dd * Dd * 2;
    float* rmsb  = (float*)(ws + o); o += (size_t)Mrows * 4;
    float* mub   = (float*)(ws + o); o += (size_t)Mrows * 4;
    float* rstdb = (float*)(ws + o); o += (size_t)Mrows * 4;
    float* bdotb = (float*)(ws + o); o += 512;
    float* gdotb = (float*)(ws + o); o += 512;

    float* out = (float*)d_out;
    float* oq  = out;                             // [M][4096]
    float* oqs = oq  + (size_t)Mrows * HnD;       // [M][32]
    float* ok  = oqs + (size_t)Mrows * Hn;        // [L][128]
    float* oks = ok  + (size_t)Lc * Dd;           // [L]
    float* ow  = oks + Lc;                        // [M][32]

    fused_prep<<<11528, 256, 0, stream>>>(
        x, xb, rmsb, mub, rstdb, wqb, qn, qns, wk, g, wpj, wt,
        hq, hk, hqt, hkt, b, bdotb, gdotb, kc, kcs, ok, oks);
    main_gemm<<<dim3(Mrows / 256, 16), 512, 0, stream>>>(
        xb, wt, rmsb, wqbs, hqt, cosr, sinr, oq, oqs);
    k_branch<<<Mrows / 32, 256, 0, stream>>>(
        xb, wt, rstdb, mub, bdotb, gdotb, hkt, cosr, sinr, idx, ok, oks, ow);
}